// Round 6
// baseline (153.124 us; speedup 1.0000x reference)
//
#include <hip/hip_runtime.h>
#include <math.h>

#define BB 512
#define SS 200
#define DD 512
#define KK 128

typedef __attribute__((ext_vector_type(8))) short bf16x8;
typedef __attribute__((ext_vector_type(4))) float f32x4;

__device__ inline unsigned short f2bf(float f) {
    union { float f; unsigned int u; } v; v.f = f;
    unsigned int r = v.u + 0x7FFFu + ((v.u >> 16) & 1u);   // RNE
    return (unsigned short)(r >> 16);
}

__device__ inline bf16x8 pack8(const float4& a, const float4& b) {
    bf16x8 p;
    p[0] = (short)f2bf(a.x); p[1] = (short)f2bf(a.y);
    p[2] = (short)f2bf(a.z); p[3] = (short)f2bf(a.w);
    p[4] = (short)f2bf(b.x); p[5] = (short)f2bf(b.y);
    p[6] = (short)f2bf(b.z); p[7] = (short)f2bf(b.w);
    return p;
}

// ---------------------------------------------------------------------------
// Wt2 in MFMA-fragment order: for k-tile t (d=t*32..), col-block n (k=n*16..),
// lane l holds 8 bf16 at Wt2[((t*8+n)*64+l)*8 + j] = W[d(t,l,j)*KK + k(n,l)]
//   k = n*16 + (l&15),  d = t*32 + (l>>4)*8 + j
// One wave's fragment load = contiguous 1KB. 128KB total, L2/L3-resident.
// ---------------------------------------------------------------------------
__global__ void wt_kernel(const float* __restrict__ W, unsigned short* __restrict__ Wt2) {
    int i = blockIdx.x * 256 + threadIdx.x;   // over 8*8*64*8 = 64K* ... (16*8*64*8=65536)
    int j = i & 7;
    int l = (i >> 3) & 63;
    int n = (i >> 9) & 7;
    int t = i >> 12;
    int k = n * 16 + (l & 15);
    int d = t * 32 + (l >> 4) * 8 + j;
    Wt2[i] = f2bf(W[d * KK + k]);
}

// ---------------------------------------------------------------------------
// Fused per-b kernel, barrier-free GEMM phase:
//   logits = sum_k tanh(tfh[b] @ W)·wpk + bias  -> softmax -> Pt[s]*tfh[b,s,:]
// 512 threads = 8 waves; wave w owns s-rows w*32..w*32+31. No LDS in GEMM.
// ---------------------------------------------------------------------------
__global__ __launch_bounds__(512, 4) void fused_kernel(
    const float* __restrict__ tfh,           // [BB,SS,DD]
    const unsigned short* __restrict__ Wt2,  // fragment-ordered [16][8][64][8]
    const float* __restrict__ wpk,           // [KK]
    const float* __restrict__ bias,          // [SS]
    float* __restrict__ out)                 // [BB,SS,DD]
{
    __shared__ float logit_s[256];
    __shared__ float Pt[SS];
    __shared__ float wpart[8];

    int tid = threadIdx.x;
    int w   = tid >> 6;        // wave 0..7
    int l   = tid & 63;
    int l15 = l & 15;
    int g   = l >> 4;
    int b   = blockIdx.x;
    const float* Ab = tfh + (size_t)b * SS * DD;

    // A addressing: this thread's two rows, 8 contiguous d at g*8
    int row0 = w * 32 + l15;
    int row1 = row0 + 16;
    bool v0 = row0 < SS, v1 = row1 < SS;
    const float* a0 = Ab + (size_t)row0 * DD + g * 8;
    const float* a1 = Ab + (size_t)row1 * DD + g * 8;
    // B addressing: lane's fragment base (advance by 8*64*8 shorts per tile)
    const unsigned short* bp = Wt2 + (size_t)l * 8;

    f32x4 acc[2][8];
    #pragma unroll
    for (int m = 0; m < 2; ++m)
        #pragma unroll
        for (int n = 0; n < 8; ++n) acc[m][n] = (f32x4){0.f, 0.f, 0.f, 0.f};

    const float4 fz = make_float4(0.f, 0.f, 0.f, 0.f);

    // prologue: A tile 0 -> regs
    float4 cA00 = v0 ? *(const float4*)(a0)     : fz;
    float4 cA01 = v0 ? *(const float4*)(a0 + 4) : fz;
    float4 cA10 = v1 ? *(const float4*)(a1)     : fz;
    float4 cA11 = v1 ? *(const float4*)(a1 + 4) : fz;

    #pragma unroll 2
    for (int t = 0; t < 16; ++t) {
        float4 nA00, nA01, nA10, nA11;
        if (t < 15) {      // prefetch next A tile early
            int d = (t + 1) * 32;
            nA00 = v0 ? *(const float4*)(a0 + d)     : fz;
            nA01 = v0 ? *(const float4*)(a0 + d + 4) : fz;
            nA10 = v1 ? *(const float4*)(a1 + d)     : fz;
            nA11 = v1 ? *(const float4*)(a1 + d + 4) : fz;
        }
        bf16x8 af0 = pack8(cA00, cA01);
        bf16x8 af1 = pack8(cA10, cA11);
        const unsigned short* bt = bp + (size_t)t * (8 * 64 * 8);
        // first 4 column-blocks
        {
            bf16x8 b0 = *(const bf16x8*)(bt);
            bf16x8 b1 = *(const bf16x8*)(bt + 1 * 512);
            bf16x8 b2 = *(const bf16x8*)(bt + 2 * 512);
            bf16x8 b3 = *(const bf16x8*)(bt + 3 * 512);
            acc[0][0] = __builtin_amdgcn_mfma_f32_16x16x32_bf16(af0, b0, acc[0][0], 0, 0, 0);
            acc[1][0] = __builtin_amdgcn_mfma_f32_16x16x32_bf16(af1, b0, acc[1][0], 0, 0, 0);
            acc[0][1] = __builtin_amdgcn_mfma_f32_16x16x32_bf16(af0, b1, acc[0][1], 0, 0, 0);
            acc[1][1] = __builtin_amdgcn_mfma_f32_16x16x32_bf16(af1, b1, acc[1][1], 0, 0, 0);
            acc[0][2] = __builtin_amdgcn_mfma_f32_16x16x32_bf16(af0, b2, acc[0][2], 0, 0, 0);
            acc[1][2] = __builtin_amdgcn_mfma_f32_16x16x32_bf16(af1, b2, acc[1][2], 0, 0, 0);
            acc[0][3] = __builtin_amdgcn_mfma_f32_16x16x32_bf16(af0, b3, acc[0][3], 0, 0, 0);
            acc[1][3] = __builtin_amdgcn_mfma_f32_16x16x32_bf16(af1, b3, acc[1][3], 0, 0, 0);
        }
        // last 4 column-blocks
        {
            bf16x8 b4 = *(const bf16x8*)(bt + 4 * 512);
            bf16x8 b5 = *(const bf16x8*)(bt + 5 * 512);
            bf16x8 b6 = *(const bf16x8*)(bt + 6 * 512);
            bf16x8 b7 = *(const bf16x8*)(bt + 7 * 512);
            acc[0][4] = __builtin_amdgcn_mfma_f32_16x16x32_bf16(af0, b4, acc[0][4], 0, 0, 0);
            acc[1][4] = __builtin_amdgcn_mfma_f32_16x16x32_bf16(af1, b4, acc[1][4], 0, 0, 0);
            acc[0][5] = __builtin_amdgcn_mfma_f32_16x16x32_bf16(af0, b5, acc[0][5], 0, 0, 0);
            acc[1][5] = __builtin_amdgcn_mfma_f32_16x16x32_bf16(af1, b5, acc[1][5], 0, 0, 0);
            acc[0][6] = __builtin_amdgcn_mfma_f32_16x16x32_bf16(af0, b6, acc[0][6], 0, 0, 0);
            acc[1][6] = __builtin_amdgcn_mfma_f32_16x16x32_bf16(af1, b6, acc[1][6], 0, 0, 0);
            acc[0][7] = __builtin_amdgcn_mfma_f32_16x16x32_bf16(af0, b7, acc[0][7], 0, 0, 0);
            acc[1][7] = __builtin_amdgcn_mfma_f32_16x16x32_bf16(af1, b7, acc[1][7], 0, 0, 0);
        }
        cA00 = nA00; cA01 = nA01; cA10 = nA10; cA11 = nA11;
    }

    // --- epilogue: tanh, weight by wpk, reduce over k; logits into LDS ---
    float wv[8];
    #pragma unroll
    for (int n = 0; n < 8; ++n) wv[n] = wpk[n * 16 + l15];

    float rs[2][4];
    #pragma unroll
    for (int m = 0; m < 2; ++m)
        #pragma unroll
        for (int r = 0; r < 4; ++r) rs[m][r] = 0.f;
    #pragma unroll
    for (int m = 0; m < 2; ++m)
        #pragma unroll
        for (int n = 0; n < 8; ++n)
            #pragma unroll
            for (int r = 0; r < 4; ++r)
                rs[m][r] += tanhf(acc[m][n][r]) * wv[n];
    #pragma unroll
    for (int m = 0; m < 2; ++m)
        #pragma unroll
        for (int r = 0; r < 4; ++r) {
            float v = rs[m][r];
            v += __shfl_xor(v, 1, 64);
            v += __shfl_xor(v, 2, 64);
            v += __shfl_xor(v, 4, 64);
            v += __shfl_xor(v, 8, 64);
            rs[m][r] = v;
        }
    if (l15 == 0) {
        #pragma unroll
        for (int m = 0; m < 2; ++m)
            #pragma unroll
            for (int r = 0; r < 4; ++r) {
                int srow = w * 32 + m * 16 + g * 4 + r;
                if (srow < SS) logit_s[srow] = rs[m][r] + bias[srow];
            }
    }
    __syncthreads();

    // --- softmax over 200 entries ---
    float v = (tid < SS) ? logit_s[tid] : -INFINITY;
    float m = v;
    #pragma unroll
    for (int off = 32; off > 0; off >>= 1) m = fmaxf(m, __shfl_xor(m, off, 64));
    if (l == 0) wpart[w] = m;
    __syncthreads();
    m = -INFINITY;
    #pragma unroll
    for (int i = 0; i < 8; ++i) m = fmaxf(m, wpart[i]);
    float e = (tid < SS) ? expf(v - m) : 0.f;
    float ssum = e;
    #pragma unroll
    for (int off = 32; off > 0; off >>= 1) ssum += __shfl_xor(ssum, off, 64);
    __syncthreads();
    if (l == 0) wpart[w] = ssum;
    __syncthreads();
    ssum = 0.f;
    #pragma unroll
    for (int i = 0; i < 8; ++i) ssum += wpart[i];
    if (tid < SS) Pt[tid] = e / ssum;
    __syncthreads();

    // --- phase 3: out[s,:] = Pt[s] * tfh[b,s,:]  (re-read hits L3) ---
    const float4* src = (const float4*)Ab;
    float4*       dst = (float4*)(out + (size_t)b * SS * DD);
    const int n4 = SS * DD / 4;   // 25600; 128 float4 per s-row
    for (int i = tid; i < n4; i += 512) {
        float p = Pt[i >> 7];
        float4 x = src[i];
        x.x *= p; x.y *= p; x.z *= p; x.w *= p;
        dst[i] = x;
    }
}

// ---------------------------------------------------------------------------
extern "C" void kernel_launch(void* const* d_in, const int* in_sizes, int n_in,
                              void* d_out, int out_size, void* d_ws, size_t ws_size,
                              hipStream_t stream) {
    const float* tfh   = (const float*)d_in[1];
    const float* wVt1  = (const float*)d_in[7];
    const float* wp1   = (const float*)d_in[8];
    const float* bias1 = (const float*)d_in[9];
    float* out = (float*)d_out;

    unsigned short* Wt2 = (unsigned short*)d_ws;   // 128KB, fragment-ordered

    wt_kernel<<<(16 * 8 * 64 * 8) / 256, 256, 0, stream>>>(wVt1, Wt2);
    fused_kernel<<<BB, 512, 0, stream>>>(tfh, Wt2, wp1 + KK, bias1, out);
}

// Round 7
// 140.072 us; speedup vs baseline: 1.0932x; 1.0932x over previous
//
#include <hip/hip_runtime.h>
#include <math.h>

#define BB 512
#define SS 200
#define DD 512
#define KK 128
#define RR (BB * SS)   // 102400 rows

typedef __attribute__((ext_vector_type(8))) short bf16x8;
typedef __attribute__((ext_vector_type(4))) float f32x4;

__device__ inline unsigned short f2bf(float f) {
    union { float f; unsigned int u; } v; v.f = f;
    unsigned int r = v.u + 0x7FFFu + ((v.u >> 16) & 1u);   // RNE
    return (unsigned short)(r >> 16);
}

__device__ inline bf16x8 pack8(const float4& a, const float4& b) {
    bf16x8 p;
    p[0] = (short)f2bf(a.x); p[1] = (short)f2bf(a.y);
    p[2] = (short)f2bf(a.z); p[3] = (short)f2bf(a.w);
    p[4] = (short)f2bf(b.x); p[5] = (short)f2bf(b.y);
    p[6] = (short)f2bf(b.z); p[7] = (short)f2bf(b.w);
    return p;
}

// ---------------------------------------------------------------------------
// Wt2 in MFMA-fragment order: tile t (d=t*32..), col-block n (k=n*16..):
//   Wt2[((t*8+n)*64+l)*8 + j] = bf16(W[d(t,l,j)*KK + k(n,l)])
//   k = n*16 + (l&15),  d = t*32 + (l>>4)*8 + j
// One wave fragment = contiguous 1KB. 128KB total, L2-resident.
// ---------------------------------------------------------------------------
__global__ void wt_kernel(const float* __restrict__ W, unsigned short* __restrict__ Wt2) {
    int i = blockIdx.x * 256 + threadIdx.x;   // over 16*8*64*8 = 65536
    int j = i & 7;
    int l = (i >> 3) & 63;
    int n = (i >> 9) & 7;
    int t = i >> 12;
    int k = n * 16 + (l & 15);
    int d = t * 32 + (l >> 4) * 8 + j;
    Wt2[i] = f2bf(W[d * KK + k]);
}

// ---------------------------------------------------------------------------
// logits[row] = sum_k tanh(tfh_flat[row,:] . W[:,k]) * wpk[k] + bias[row%SS]
// Barrier-free, LDS-free: 256 threads = 4 waves, each wave 32 rows.
// A: global->reg (1-deep prefetch), convert in-reg. B: fragment-ordered L2.
// 800 blocks x 128 rows = 102400 exactly (no masking).
// ---------------------------------------------------------------------------
__global__ __launch_bounds__(256, 2) void logits_frag_kernel(
    const float* __restrict__ tfh,           // [RR, DD]
    const unsigned short* __restrict__ Wt2,  // fragment-ordered
    const float* __restrict__ wpk,           // [KK]
    const float* __restrict__ bias,          // [SS]
    float* __restrict__ logits)              // [RR]
{
    int tid = threadIdx.x;
    int w   = tid >> 6;        // wave 0..3
    int l   = tid & 63;
    int l15 = l & 15;
    int g   = l >> 4;
    int brow = blockIdx.x * 128;

    int row0 = brow + w * 32 + l15;
    const float* a0 = tfh + (size_t)row0 * DD + g * 8;
    const float* a1 = a0 + 16 * DD;
    const unsigned short* bp = Wt2 + (size_t)l * 8;

    f32x4 acc[2][8];
    #pragma unroll
    for (int m = 0; m < 2; ++m)
        #pragma unroll
        for (int n = 0; n < 8; ++n) acc[m][n] = (f32x4){0.f, 0.f, 0.f, 0.f};

    // prologue
    float4 cA00 = *(const float4*)(a0);
    float4 cA01 = *(const float4*)(a0 + 4);
    float4 cA10 = *(const float4*)(a1);
    float4 cA11 = *(const float4*)(a1 + 4);

    #pragma unroll 2
    for (int t = 0; t < 16; ++t) {
        float4 nA00, nA01, nA10, nA11;
        if (t < 15) {
            int d = (t + 1) * 32;
            nA00 = *(const float4*)(a0 + d);
            nA01 = *(const float4*)(a0 + d + 4);
            nA10 = *(const float4*)(a1 + d);
            nA11 = *(const float4*)(a1 + d + 4);
        }
        bf16x8 af0 = pack8(cA00, cA01);
        bf16x8 af1 = pack8(cA10, cA11);
        const unsigned short* bt = bp + (size_t)t * (8 * 64 * 8);
        {
            bf16x8 b0 = *(const bf16x8*)(bt);
            bf16x8 b1 = *(const bf16x8*)(bt + 1 * 512);
            bf16x8 b2 = *(const bf16x8*)(bt + 2 * 512);
            bf16x8 b3 = *(const bf16x8*)(bt + 3 * 512);
            acc[0][0] = __builtin_amdgcn_mfma_f32_16x16x32_bf16(af0, b0, acc[0][0], 0, 0, 0);
            acc[1][0] = __builtin_amdgcn_mfma_f32_16x16x32_bf16(af1, b0, acc[1][0], 0, 0, 0);
            acc[0][1] = __builtin_amdgcn_mfma_f32_16x16x32_bf16(af0, b1, acc[0][1], 0, 0, 0);
            acc[1][1] = __builtin_amdgcn_mfma_f32_16x16x32_bf16(af1, b1, acc[1][1], 0, 0, 0);
            acc[0][2] = __builtin_amdgcn_mfma_f32_16x16x32_bf16(af0, b2, acc[0][2], 0, 0, 0);
            acc[1][2] = __builtin_amdgcn_mfma_f32_16x16x32_bf16(af1, b2, acc[1][2], 0, 0, 0);
            acc[0][3] = __builtin_amdgcn_mfma_f32_16x16x32_bf16(af0, b3, acc[0][3], 0, 0, 0);
            acc[1][3] = __builtin_amdgcn_mfma_f32_16x16x32_bf16(af1, b3, acc[1][3], 0, 0, 0);
        }
        {
            bf16x8 b4 = *(const bf16x8*)(bt + 4 * 512);
            bf16x8 b5 = *(const bf16x8*)(bt + 5 * 512);
            bf16x8 b6 = *(const bf16x8*)(bt + 6 * 512);
            bf16x8 b7 = *(const bf16x8*)(bt + 7 * 512);
            acc[0][4] = __builtin_amdgcn_mfma_f32_16x16x32_bf16(af0, b4, acc[0][4], 0, 0, 0);
            acc[1][4] = __builtin_amdgcn_mfma_f32_16x16x32_bf16(af1, b4, acc[1][4], 0, 0, 0);
            acc[0][5] = __builtin_amdgcn_mfma_f32_16x16x32_bf16(af0, b5, acc[0][5], 0, 0, 0);
            acc[1][5] = __builtin_amdgcn_mfma_f32_16x16x32_bf16(af1, b5, acc[1][5], 0, 0, 0);
            acc[0][6] = __builtin_amdgcn_mfma_f32_16x16x32_bf16(af0, b6, acc[0][6], 0, 0, 0);
            acc[1][6] = __builtin_amdgcn_mfma_f32_16x16x32_bf16(af1, b6, acc[1][6], 0, 0, 0);
            acc[0][7] = __builtin_amdgcn_mfma_f32_16x16x32_bf16(af0, b7, acc[0][7], 0, 0, 0);
            acc[1][7] = __builtin_amdgcn_mfma_f32_16x16x32_bf16(af1, b7, acc[1][7], 0, 0, 0);
        }
        cA00 = nA00; cA01 = nA01; cA10 = nA10; cA11 = nA11;
    }

    // epilogue: tanh, weight by wpk, reduce over k within 16-lane group
    float wv[8];
    #pragma unroll
    for (int n = 0; n < 8; ++n) wv[n] = wpk[n * 16 + l15];

    float rs[2][4];
    #pragma unroll
    for (int m = 0; m < 2; ++m)
        #pragma unroll
        for (int r = 0; r < 4; ++r) rs[m][r] = 0.f;
    #pragma unroll
    for (int m = 0; m < 2; ++m)
        #pragma unroll
        for (int n = 0; n < 8; ++n)
            #pragma unroll
            for (int r = 0; r < 4; ++r)
                rs[m][r] += tanhf(acc[m][n][r]) * wv[n];
    #pragma unroll
    for (int m = 0; m < 2; ++m)
        #pragma unroll
        for (int r = 0; r < 4; ++r) {
            float v = rs[m][r];
            v += __shfl_xor(v, 1, 64);
            v += __shfl_xor(v, 2, 64);
            v += __shfl_xor(v, 4, 64);
            v += __shfl_xor(v, 8, 64);
            rs[m][r] = v;
        }
    if (l15 == 0) {
        #pragma unroll
        for (int m = 0; m < 2; ++m)
            #pragma unroll
            for (int r = 0; r < 4; ++r) {
                int grow = brow + w * 32 + m * 16 + g * 4 + r;
                int s = grow % SS;
                logits[grow] = rs[m][r] + bias[s];
            }
    }
}

// ---------------------------------------------------------------------------
// Pt = softmax(logits[b,:]); out[b,s,:] = Pt[s] * tfh[b,s,:]
// tfh re-read hits L3 (resident from GEMM); out stores NON-TEMPORAL so they
// don't evict tfh from L3.
// ---------------------------------------------------------------------------
__global__ __launch_bounds__(1024) void softmax_mul_kernel(
    const float* __restrict__ logits,
    const float* __restrict__ tfh,
    float* __restrict__ out)
{
    int b = blockIdx.x;
    int tid = threadIdx.x;
    __shared__ float Pt[SS];
    __shared__ float wpart[16];

    float v = (tid < SS) ? logits[(size_t)b * SS + tid] : -INFINITY;
    float m = v;
    #pragma unroll
    for (int off = 32; off > 0; off >>= 1) m = fmaxf(m, __shfl_xor(m, off, 64));
    if ((tid & 63) == 0) wpart[tid >> 6] = m;
    __syncthreads();
    m = -INFINITY;
    #pragma unroll
    for (int i = 0; i < 16; ++i) m = fmaxf(m, wpart[i]);
    float e = (tid < SS) ? expf(v - m) : 0.f;
    float ssum = e;
    #pragma unroll
    for (int off = 32; off > 0; off >>= 1) ssum += __shfl_xor(ssum, off, 64);
    __syncthreads();
    if ((tid & 63) == 0) wpart[tid >> 6] = ssum;
    __syncthreads();
    ssum = 0.f;
    #pragma unroll
    for (int i = 0; i < 16; ++i) ssum += wpart[i];
    if (tid < SS) Pt[tid] = e / ssum;
    __syncthreads();

    const f32x4* src = (const f32x4*)(tfh + (size_t)b * SS * DD);
    f32x4*       dst = (f32x4*)(out + (size_t)b * SS * DD);
    const int n4 = SS * DD / 4;   // 25600; 128 f32x4 per s-row
    for (int i = tid; i < n4; i += 1024) {
        float p = Pt[i >> 7];
        f32x4 x = src[i];
        x = x * p;
        __builtin_nontemporal_store(x, dst + i);
    }
}

// ---------------------------------------------------------------------------
extern "C" void kernel_launch(void* const* d_in, const int* in_sizes, int n_in,
                              void* d_out, int out_size, void* d_ws, size_t ws_size,
                              hipStream_t stream) {
    const float* tfh   = (const float*)d_in[1];
    const float* wVt1  = (const float*)d_in[7];
    const float* wp1   = (const float*)d_in[8];
    const float* bias1 = (const float*)d_in[9];
    float* out = (float*)d_out;

    // ws: Wt2 bf16 fragment-ordered (128KB) | logits f32 [RR] (400KB)
    unsigned short* Wt2 = (unsigned short*)d_ws;
    float* logits = (float*)((char*)d_ws + 16 * 8 * 64 * 8 * sizeof(unsigned short));

    wt_kernel<<<(16 * 8 * 64 * 8) / 256, 256, 0, stream>>>(wVt1, Wt2);
    logits_frag_kernel<<<RR / 128, 256, 0, stream>>>(tfh, Wt2, wp1 + KK, bias1, logits);
    softmax_mul_kernel<<<BB, 1024, 0, stream>>>(logits, tfh, out);
}

// Round 8
// 116.509 us; speedup vs baseline: 1.3143x; 1.2022x over previous
//
#include <hip/hip_runtime.h>
#include <math.h>

#define BB 512
#define SS 200
#define DD 512
#define KK 128
#define RR (BB * SS)   // 102400 rows

typedef __attribute__((ext_vector_type(8))) short bf16x8;
typedef __attribute__((ext_vector_type(4))) short bf16x4;
typedef __attribute__((ext_vector_type(4))) float f32x4;

__device__ inline unsigned short f2bf(float f) {
    union { float f; unsigned int u; } v; v.f = f;
    unsigned int r = v.u + 0x7FFFu + ((v.u >> 16) & 1u);   // RNE
    return (unsigned short)(r >> 16);
}

__device__ inline float fast_tanh(float x) {
    x = fminf(10.f, fmaxf(-10.f, x));
    float t = exp2f(x * 2.885390081777927f);          // e^(2x)
    return (t - 1.f) * __builtin_amdgcn_rcpf(t + 1.f);
}

// ---------------------------------------------------------------------------
// Wt2 in MFMA-fragment order: tile t (d=t*32..), col-block n (k=n*16..):
//   Wt2[((t*8+n)*64+l)*8 + j] = bf16(W[d(t,l,j)*KK + k(n,l)])
//   k = n*16 + (l&15),  d = t*32 + (l>>4)*8 + j
// One wave fragment = contiguous 1KB. 128KB total, L2-resident.
// ---------------------------------------------------------------------------
__global__ void wt_kernel(const float* __restrict__ W, unsigned short* __restrict__ Wt2) {
    int i = blockIdx.x * 256 + threadIdx.x;   // over 16*8*64*8 = 65536
    int j = i & 7;
    int l = (i >> 3) & 63;
    int n = (i >> 9) & 7;
    int t = i >> 12;
    int k = n * 16 + (l & 15);
    int d = t * 32 + (l >> 4) * 8 + j;
    Wt2[i] = f2bf(W[d * KK + k]);
}

// ---------------------------------------------------------------------------
// logits[row] = sum_k tanh(tfh[row,:] . W[:,k]) * wpk[k] + bias[row%SS]
// A: LDS-staged (bf16, contiguous-coalesced loads), single-buffered.
// B: fragment-ordered, direct from L2 (no LDS).
// 800 blocks x 256 thr (4 waves, wave w owns rows w*32..+31), 4 blocks/CU.
// ---------------------------------------------------------------------------
__global__ __launch_bounds__(256, 4) void logits_kernel(
    const float* __restrict__ tfh,           // [RR, DD]
    const unsigned short* __restrict__ Wt2,  // fragment-ordered
    const float* __restrict__ wpk,           // [KK]
    const float* __restrict__ bias,          // [SS]
    float* __restrict__ logits)              // [RR]
{
    __shared__ unsigned short As[128][40];   // bf16 A tile, padded stride

    int tid = threadIdx.x;
    int w   = tid >> 6;        // wave 0..3
    int l   = tid & 63;
    int l15 = l & 15;
    int g   = l >> 4;
    int brow = blockIdx.x * 128;

    // staging map: f = tid + 256*jj -> row r0+32*jj (r0=tid>>3), float4-col c4=tid&7
    // => 8 consecutive lanes read one full 128B row segment (perfect coalescing)
    int r0 = tid >> 3;
    int c4 = tid & 7;
    const float* ap = tfh + (size_t)(brow + r0) * DD + c4 * 4;

    // B fragment base for this lane
    const unsigned short* bp = Wt2 + (size_t)l * 8;

    f32x4 acc[2][8];
    #pragma unroll
    for (int m = 0; m < 2; ++m)
        #pragma unroll
        for (int n = 0; n < 8; ++n) acc[m][n] = (f32x4){0.f, 0.f, 0.f, 0.f};

    for (int t = 0; t < 16; ++t) {
        int d0 = t * 32;
        // --- stage A: 128 rows x 32 d, fp32 -> bf16 ---
        #pragma unroll
        for (int jj = 0; jj < 4; ++jj) {
            float4 v = *(const float4*)(ap + d0 + (size_t)(32 * jj) * DD);
            bf16x4 p;
            p[0] = (short)f2bf(v.x); p[1] = (short)f2bf(v.y);
            p[2] = (short)f2bf(v.z); p[3] = (short)f2bf(v.w);
            *(bf16x4*)&As[r0 + 32 * jj][c4 * 4] = p;
        }
        __syncthreads();
        // --- MFMA: wave w rows, B fragments straight from L2 ---
        bf16x8 af0 = *(const bf16x8*)&As[w * 32 + l15][g * 8];
        bf16x8 af1 = *(const bf16x8*)&As[w * 32 + 16 + l15][g * 8];
        const unsigned short* bt = bp + (size_t)t * (8 * 64 * 8);
        #pragma unroll
        for (int nb = 0; nb < 4; ++nb) {
            bf16x8 b0 = *(const bf16x8*)(bt + (2 * nb) * 512);
            bf16x8 b1 = *(const bf16x8*)(bt + (2 * nb + 1) * 512);
            acc[0][2*nb]   = __builtin_amdgcn_mfma_f32_16x16x32_bf16(af0, b0, acc[0][2*nb],   0, 0, 0);
            acc[1][2*nb]   = __builtin_amdgcn_mfma_f32_16x16x32_bf16(af1, b0, acc[1][2*nb],   0, 0, 0);
            acc[0][2*nb+1] = __builtin_amdgcn_mfma_f32_16x16x32_bf16(af0, b1, acc[0][2*nb+1], 0, 0, 0);
            acc[1][2*nb+1] = __builtin_amdgcn_mfma_f32_16x16x32_bf16(af1, b1, acc[1][2*nb+1], 0, 0, 0);
        }
        __syncthreads();
    }

    // --- epilogue: tanh, weight by wpk, reduce over k within 16-lane group ---
    float wv[8];
    #pragma unroll
    for (int n = 0; n < 8; ++n) wv[n] = wpk[n * 16 + l15];

    float rs[2][4];
    #pragma unroll
    for (int m = 0; m < 2; ++m)
        #pragma unroll
        for (int r = 0; r < 4; ++r) rs[m][r] = 0.f;
    #pragma unroll
    for (int m = 0; m < 2; ++m)
        #pragma unroll
        for (int n = 0; n < 8; ++n)
            #pragma unroll
            for (int r = 0; r < 4; ++r)
                rs[m][r] += fast_tanh(acc[m][n][r]) * wv[n];
    #pragma unroll
    for (int m = 0; m < 2; ++m)
        #pragma unroll
        for (int r = 0; r < 4; ++r) {
            float v = rs[m][r];
            v += __shfl_xor(v, 1, 64);
            v += __shfl_xor(v, 2, 64);
            v += __shfl_xor(v, 4, 64);
            v += __shfl_xor(v, 8, 64);
            rs[m][r] = v;
        }
    if (l15 == 0) {
        #pragma unroll
        for (int m = 0; m < 2; ++m)
            #pragma unroll
            for (int r = 0; r < 4; ++r) {
                int grow = brow + w * 32 + m * 16 + g * 4 + r;
                logits[grow] = rs[m][r] + bias[grow % SS];
            }
    }
}

// ---------------------------------------------------------------------------
// Pt = softmax(logits[b,:]); out[b,s,:] = Pt[s] * tfh[b,s,:]
// tfh re-read hits L3; non-temporal stores keep tfh resident.
// ---------------------------------------------------------------------------
__global__ __launch_bounds__(1024) void softmax_mul_kernel(
    const float* __restrict__ logits,
    const float* __restrict__ tfh,
    float* __restrict__ out)
{
    int b = blockIdx.x;
    int tid = threadIdx.x;
    __shared__ float Pt[SS];
    __shared__ float wpart[16];

    float v = (tid < SS) ? logits[(size_t)b * SS + tid] : -INFINITY;
    float m = v;
    #pragma unroll
    for (int off = 32; off > 0; off >>= 1) m = fmaxf(m, __shfl_xor(m, off, 64));
    if ((tid & 63) == 0) wpart[tid >> 6] = m;
    __syncthreads();
    m = -INFINITY;
    #pragma unroll
    for (int i = 0; i < 16; ++i) m = fmaxf(m, wpart[i]);
    float e = (tid < SS) ? expf(v - m) : 0.f;
    float ssum = e;
    #pragma unroll
    for (int off = 32; off > 0; off >>= 1) ssum += __shfl_xor(ssum, off, 64);
    __syncthreads();
    if ((tid & 63) == 0) wpart[tid >> 6] = ssum;
    __syncthreads();
    ssum = 0.f;
    #pragma unroll
    for (int i = 0; i < 16; ++i) ssum += wpart[i];
    if (tid < SS) Pt[tid] = e / ssum;
    __syncthreads();

    const f32x4* src = (const f32x4*)(tfh + (size_t)b * SS * DD);
    f32x4*       dst = (f32x4*)(out + (size_t)b * SS * DD);
    const int n4 = SS * DD / 4;   // 25600; 128 f32x4 per s-row
    for (int i = tid; i < n4; i += 1024) {
        float p = Pt[i >> 7];
        f32x4 x = src[i];
        x = x * p;
        __builtin_nontemporal_store(x, dst + i);
    }
}

// ---------------------------------------------------------------------------
extern "C" void kernel_launch(void* const* d_in, const int* in_sizes, int n_in,
                              void* d_out, int out_size, void* d_ws, size_t ws_size,
                              hipStream_t stream) {
    const float* tfh   = (const float*)d_in[1];
    const float* wVt1  = (const float*)d_in[7];
    const float* wp1   = (const float*)d_in[8];
    const float* bias1 = (const float*)d_in[9];
    float* out = (float*)d_out;

    // ws: Wt2 bf16 fragment-ordered (128KB) | logits f32 [RR] (400KB)
    unsigned short* Wt2 = (unsigned short*)d_ws;
    float* logits = (float*)((char*)d_ws + 16 * 8 * 64 * 8 * sizeof(unsigned short));

    wt_kernel<<<(16 * 8 * 64 * 8) / 256, 256, 0, stream>>>(wVt1, Wt2);
    logits_kernel<<<RR / 128, 256, 0, stream>>>(tfh, Wt2, wp1 + KK, bias1, logits);
    softmax_mul_kernel<<<BB, 1024, 0, stream>>>(logits, tfh, out);
}